// Round 4
// baseline (405.390 us; speedup 1.0000x reference)
//
#include <hip/hip_runtime.h>
#include <cstddef>

#define BB    16
#define NN    2048
#define BN    (BB * NN)
#define EPSF  1e-9f
#define TPB   256
#define NPAIR 4                 // 8 columns/rows per thread as 4 float2 pairs
#define SPLIT 32                // reduction-dim split
#define TILE  64                // NN/SPLIT staged points per block
#define PIDX(s, b, i) ((((size_t)(s)) * BB + (b)) * NN + (i))

typedef float f2 __attribute__((ext_vector_type(2)));

__device__ __forceinline__ float fast_exp2(float x) {
#if __has_builtin(__builtin_amdgcn_exp2f)
    return __builtin_amdgcn_exp2f(x);
#else
    return exp2f(x);
#endif
}

// passA: fused combB(k-1) + column sums of round k.
//   prologue: sum prev RS/RR partials (32 slices, distributed over 4 waves),
//             cur_k = max(cur_{k-1}(1-rs),0), out += cur_{k-1}*rr,
//             stage (px,py,pz,c1*pn)+cu for TILE rows.
//   main:     Sp/Tp[split] = per-column partial sums over this block's rows.
__global__ __launch_bounds__(TPB) void passA(
    const float* __restrict__ preds, const float* __restrict__ labels,
    const float* __restrict__ curprev, float* __restrict__ curout,
    const float* __restrict__ RSp, const float* __restrict__ RRp,
    float* __restrict__ Sp, float* __restrict__ Tp,
    float* __restrict__ out, float c1, int k)
{
    __shared__ float4 s_p[TILE];
    __shared__ float  s_cu[TILE];
    __shared__ float  s_ws[2][4][TILE];
    int blk = blockIdx.x;
    int split = blk & (SPLIT - 1), b = blk >> 5;
    int t = threadIdx.x;
    int base = b * NN;
    int r = t & (TILE - 1), w = t >> 6;

    if (k > 0) {                         // distributed 32-slice partial sums
        float aRS = 0.f, aRR = 0.f;
#pragma unroll
        for (int s8 = 0; s8 < SPLIT / 4; s8++) {
            int s = w * (SPLIT / 4) + s8;
            aRS += RSp[PIDX(s, b, split * TILE + r)];
            aRR += RRp[PIDX(s, b, split * TILE + r)];
        }
        s_ws[0][w][r] = aRS;
        s_ws[1][w][r] = aRR;
    }
    __syncthreads();

    if (t < TILE) {                      // exactly wave 0
        int idx = base + split * TILE + t;
        const float* p = preds + (size_t)idx * 3;
        float px = p[0], py = p[1], pz = p[2];
        float pn = px * px + py * py + pz * pz;
        float cu, contrib = 0.f;
        if (k == 0) cu = 1.f;
        else {
            float rs = s_ws[0][0][t] + s_ws[0][1][t] + s_ws[0][2][t] + s_ws[0][3][t];
            float rr = s_ws[1][0][t] + s_ws[1][1][t] + s_ws[1][2][t] + s_ws[1][3][t];
            float cup = curprev[idx];
            contrib = cup * rr;
            cu = fmaxf(cup * (1.f - rs), 0.f);
        }
        s_p[t]  = make_float4(px, py, pz, c1 * pn);
        s_cu[t] = cu;
        curout[idx] = cu;
        if (k > 0) {
#pragma unroll
            for (int o = 32; o > 0; o >>= 1) contrib += __shfl_down(contrib, o, 64);
            if (t == 0) atomicAdd(out, contrib);
        }
    }

    // thread-held columns (labels), prescaled, as float2 pairs
    f2 gx[NPAIR], gy[NPAIR], gz[NPAIR], am[NPAIR], Sa[NPAIR], Ta[NPAIR];
    float n2c1 = -2.f * c1;
#pragma unroll
    for (int p = 0; p < NPAIR; p++) {
        int m0 = t + (2 * p) * TPB, m1 = t + (2 * p + 1) * TPB;
        const float* l0 = labels + (size_t)(base + m0) * 3;
        const float* l1 = labels + (size_t)(base + m1) * 3;
        float ax = l0[0], ay = l0[1], az = l0[2];
        float bx = l1[0], by = l1[1], bz = l1[2];
        gx[p] = (f2){n2c1 * ax, n2c1 * bx};
        gy[p] = (f2){n2c1 * ay, n2c1 * by};
        gz[p] = (f2){n2c1 * az, n2c1 * bz};
        am[p] = (f2){c1 * (ax * ax + ay * ay + az * az),
                     c1 * (bx * bx + by * by + bz * bz)};
        Sa[p] = (f2){0.f, 0.f};
        Ta[p] = (f2){0.f, 0.f};
    }
    __syncthreads();

#pragma unroll 4
    for (int j = 0; j < TILE; j++) {
        float4 P = s_p[j];
        float cuj = s_cu[j];
#pragma unroll
        for (int p = 0; p < NPAIR; p++) {
            f2 arg = P.x * gx[p] + (P.y * gy[p] + (P.z * gz[p] + (am[p] + P.w)));
            f2 e;
            e.x = fast_exp2(arg.x);
            e.y = fast_exp2(arg.y);
            Sa[p] += e;
            Ta[p] += e * cuj;
        }
    }
#pragma unroll
    for (int p = 0; p < NPAIR; p++) {
        int m0 = t + (2 * p) * TPB, m1 = t + (2 * p + 1) * TPB;
        Sp[PIDX(split, b, m0)] = Sa[p].x;
        Sp[PIDX(split, b, m1)] = Sa[p].y;
        Tp[PIDX(split, b, m0)] = Ta[p].x;
        Tp[PIDX(split, b, m1)] = Ta[p].y;
    }
}

// passB: fused combA + row sums of round k.
//   prologue: sum S/T partials for TILE columns, compute cc & cost_{k+1},
//             stage (gx',gy',gz',h)+cc (or raw label data on the last round).
//   main:     RSp/RRp[split] = per-row partial sums over this block's columns.
__global__ __launch_bounds__(TPB) void passB(
    const float* __restrict__ preds, const float* __restrict__ labels,
    const float* __restrict__ Sp, const float* __restrict__ Tp,
    const float* __restrict__ costprev, float* __restrict__ costout,
    float* __restrict__ RSp, float* __restrict__ RRp,
    float c1, float invc1, int k, int last)
{
    __shared__ float4 s_l[TILE];
    __shared__ float  s_cc[TILE];
    __shared__ float  s_ws[2][4][TILE];
    int blk = blockIdx.x;
    int split = blk & (SPLIT - 1), b = blk >> 5;
    int t = threadIdx.x;
    int base = b * NN;
    int r = t & (TILE - 1), w = t >> 6;

    {
        float aS = 0.f, aT = 0.f;
#pragma unroll
        for (int s8 = 0; s8 < SPLIT / 4; s8++) {
            int s = w * (SPLIT / 4) + s8;
            aS += Sp[PIDX(s, b, split * TILE + r)];
            aT += Tp[PIDX(s, b, split * TILE + r)];
        }
        s_ws[0][w][r] = aS;
        s_ws[1][w][r] = aT;
    }
    __syncthreads();

    if (t < TILE) {
        int idx = base + split * TILE + t;
        const float* l = preds ? labels + (size_t)idx * 3 : nullptr;
        float lx = l[0], ly = l[1], lz = l[2];
        float lm2 = lx * lx + ly * ly + lz * lz;
        float S = s_ws[0][0][t] + s_ws[0][1][t] + s_ws[0][2][t] + s_ws[0][3][t];
        float T = s_ws[1][0][t] + s_ws[1][1][t] + s_ws[1][2][t] + s_ws[1][3][t];
        float cost = (k == 0) ? 1.f : costprev[idx];
        float D1 = fmaf(cost, S, EPSF);
        float S2 = cost * T / D1;
        float bw = fminf(cost / (S2 + EPSF), 1.f);
        float cc = cost * bw / D1;
        costout[idx] = fmaxf(fmaf(-S2, bw, cost), 0.f);
        if (last) s_l[t] = make_float4(lx, ly, lz, lm2);
        else      s_l[t] = make_float4(-2.f * c1 * lx, -2.f * c1 * ly,
                                       -2.f * c1 * lz, c1 * lm2);
        s_cc[t] = cc;
    }

    f2 qx[NPAIR], qy[NPAIR], qz[NPAIR], qn[NPAIR], RSa[NPAIR], RRa[NPAIR];
#pragma unroll
    for (int p = 0; p < NPAIR; p++) {
        int n0 = t + (2 * p) * TPB, n1 = t + (2 * p + 1) * TPB;
        const float* p0 = preds + (size_t)(base + n0) * 3;
        const float* p1 = preds + (size_t)(base + n1) * 3;
        float ax = p0[0], ay = p0[1], az = p0[2];
        float bx = p1[0], by = p1[1], bz = p1[2];
        qx[p] = (f2){ax, bx};
        qy[p] = (f2){ay, by};
        qz[p] = (f2){az, bz};
        float pn0 = ax * ax + ay * ay + az * az;
        float pn1 = bx * bx + by * by + bz * bz;
        qn[p] = last ? (f2){pn0, pn1} : (f2){c1 * pn0, c1 * pn1};
        RSa[p] = (f2){0.f, 0.f};
        RRa[p] = (f2){0.f, 0.f};
    }
    __syncthreads();

    if (!last) {
#pragma unroll 4
        for (int j = 0; j < TILE; j++) {
            float4 L = s_l[j];
            float ccj = s_cc[j];
#pragma unroll
            for (int p = 0; p < NPAIR; p++) {
                f2 arg = qx[p] * L.x + (qy[p] * L.y + (qz[p] * L.z + (qn[p] + L.w)));
                f2 e;
                e.x = fast_exp2(arg.x);
                e.y = fast_exp2(arg.y);
                f2 wv = e * ccj;
                RSa[p] += wv;
                RRa[p] += wv * arg;          // sum w*arg; *1/c1 at store
            }
        }
#pragma unroll
        for (int p = 0; p < NPAIR; p++) {
            int n0 = t + (2 * p) * TPB, n1 = t + (2 * p + 1) * TPB;
            RSp[PIDX(split, b, n0)] = RSa[p].x;
            RSp[PIDX(split, b, n1)] = RSa[p].y;
            RRp[PIDX(split, b, n0)] = RRa[p].x * invc1;
            RRp[PIDX(split, b, n1)] = RRa[p].y * invc1;
        }
    } else {                                  // ef = 0: e == 1, accumulate cc*pw
#pragma unroll 4
        for (int j = 0; j < TILE; j++) {
            float4 L = s_l[j];
            float ccj = s_cc[j];
#pragma unroll
            for (int p = 0; p < NPAIR; p++) {
                f2 dot = qx[p] * L.x + (qy[p] * L.y + qz[p] * L.z);
                f2 pw  = (qn[p] + L.w) - 2.f * dot;
                RRa[p] += ccj * pw;
            }
        }
#pragma unroll
        for (int p = 0; p < NPAIR; p++) {
            int n0 = t + (2 * p) * TPB, n1 = t + (2 * p + 1) * TPB;
            RRp[PIDX(split, b, n0)] = RRa[p].x;
            RRp[PIDX(split, b, n1)] = RRa[p].y;
        }
    }
}

// out += sum_n cur_9[n] * (sum_s RRp[s][n])
__global__ __launch_bounds__(TPB) void finalK(const float* __restrict__ cur,
                                              const float* __restrict__ RRp,
                                              float* __restrict__ out)
{
    int t = threadIdx.x;
    int i = blockIdx.x * TPB + t;
    int b = i >> 11, n = i & (NN - 1);
    float acc = 0.f;
#pragma unroll
    for (int s = 0; s < SPLIT; s++) acc += RRp[PIDX(s, b, n)];
    float contrib = cur[i] * acc;
#pragma unroll
    for (int o = 32; o > 0; o >>= 1) contrib += __shfl_down(contrib, o, 64);
    __shared__ float s_red[TPB / 64];
    if ((t & 63) == 0) s_red[t >> 6] = contrib;
    __syncthreads();
    if (t == 0) {
        float s = 0.f;
#pragma unroll
        for (int wv = 0; wv < TPB / 64; wv++) s += s_red[wv];
        atomicAdd(out, s);
    }
}

extern "C" void kernel_launch(void* const* d_in, const int* in_sizes, int n_in,
                              void* d_out, int out_size, void* d_ws, size_t ws_size,
                              hipStream_t stream) {
    const float* preds  = (const float*)d_in[0];
    const float* labels = (const float*)d_in[1];
    float* out = (float*)d_out;
    float* ws  = (float*)d_ws;

    const size_t PSZ = (size_t)SPLIT * BB * NN;   // 1M floats per partial array
    float* Sp  = ws;
    float* Tp  = ws + PSZ;
    float* RSp = ws + 2 * PSZ;
    float* RRp = ws + 3 * PSZ;
    float* curb[2]  = {ws + 4 * PSZ,          ws + 4 * PSZ + BN};
    float* costb[2] = {ws + 4 * PSZ + 2 * BN, ws + 4 * PSZ + 3 * BN};
    // total: 16 MB + 512 KB — every slot written before read each call.

    hipMemsetAsync(d_out, 0, sizeof(float), stream);

    static const float efs[10] = {-16384.0f, -4096.0f, -1024.0f, -256.0f, -64.0f,
                                  -16.0f, -4.0f, -1.0f, -0.25f, 0.0f};
    const float log2e = 1.44269504088896f;
    const int grid = BB * SPLIT;   // 512 blocks
    for (int k = 0; k < 10; k++) {
        float c1 = efs[k] * log2e;
        float invc1 = (efs[k] != 0.0f) ? 1.0f / c1 : 0.0f;
        passA<<<grid, TPB, 0, stream>>>(preds, labels,
            curb[(k + 1) & 1], curb[k & 1],
            RSp, RRp, Sp, Tp, out, c1, k);
        passB<<<grid, TPB, 0, stream>>>(preds, labels,
            Sp, Tp,
            costb[k & 1], costb[(k + 1) & 1],
            RSp, RRp,
            c1, invc1, k, (k == 9) ? 1 : 0);
    }
    finalK<<<BN / TPB, TPB, 0, stream>>>(curb[1], RRp, out);
}